// Round 8
// baseline (331.672 us; speedup 1.0000x reference)
//
#include <hip/hip_runtime.h>
#include <hip/hip_fp16.h>
#include <stdint.h>

// Problem constants
#define B_ 32
#define T_ 2048
#define D_ 512
#define U_ 512
#define M_ (B_ * T_)
#define MAXC 4

// GEMM (r1-proven flow, occupancy-tuned): 512 thr, BM=64, BN=256 (NSPLIT=2),
// BK=32, single-buffered LDS, 2 barriers/iter, wave = 64 rows x 32 cols
// (acc[4][2] = 32 VGPRs). LDS 23.5 KB -> up to 6 blocks/CU; lb(512,5).
#define BK 32
#define SAW 40           // sA row stride in halves (80 B; 2-way max on frag reads)

typedef _Float16 half8   __attribute__((ext_vector_type(8)));
typedef _Float16 half4_t __attribute__((ext_vector_type(4)));
typedef float   floatx4  __attribute__((ext_vector_type(4)));

__device__ __forceinline__ float tanh_fast(float x) {
    float ax = fabsf(x);
    float e  = __expf(2.0f * ax);
    float t  = 1.0f - 2.0f / (e + 1.0f);
    return copysignf(t, x);
}

// async global->LDS, 16B per lane. LDS dest is wave-uniform base + lane*16.
__device__ __forceinline__ void gld_lds16(const void* gsrc, void* lds_dst) {
    typedef __attribute__((address_space(1))) const char gch;
    typedef __attribute__((address_space(3))) char lch;
    __builtin_amdgcn_global_load_lds((const gch*)(uintptr_t)gsrc,
                                     (lch*)(uint32_t)(uintptr_t)lds_dst,
                                     16, 0, 0);
}

// ---------------- k_prep: fused {W1 -> W1T fp16 transpose} + {w2q = query @ W2} ----
__global__ __launch_bounds__(256)
void k_prep(const float* __restrict__ W1, const float* __restrict__ query,
            const float* __restrict__ W2, _Float16* __restrict__ W1T,
            float* __restrict__ w2q) {
    const int bid = blockIdx.x;
    const int tid = threadIdx.x;
    if (bid < 64) {
        __shared__ float tile[64][65];
        const int bx = bid & 7;          // k-tile
        const int by = bid >> 3;         // n-tile
        const int k0 = bx * 64, n0 = by * 64;
        const int tx = tid & 63;
        const int ty = tid >> 6;         // 0..3
#pragma unroll
        for (int i = 0; i < 16; ++i) {
            int r = ty * 16 + i;
            tile[r][tx] = W1[(size_t)(k0 + r) * U_ + n0 + tx];
        }
        __syncthreads();
#pragma unroll
        for (int i = 0; i < 16; ++i) {
            int r = ty * 16 + i;
            W1T[(size_t)(n0 + r) * D_ + k0 + tx] = (_Float16)tile[tx][r];
        }
    } else {
        __shared__ float sq[D_];
        __shared__ float part[128];
        const int id = bid - 64;
        const int b  = id >> 2;          // 0..31
        const int nq = id & 3;           // n-chunk of 128
        sq[tid]       = query[b * D_ + tid];
        sq[tid + 256] = query[b * D_ + tid + 256];
        __syncthreads();
        const int n  = nq * 128 + (tid & 127);
        const int dh = tid >> 7;         // 0/1 -> d-half
        float acc = 0.f;
        const int d0 = dh * 256;
#pragma unroll 16
        for (int d = d0; d < d0 + 256; ++d)
            acc = fmaf(sq[d], W2[(size_t)d * U_ + n], acc);
        if (dh == 1) part[tid & 127] = acc;
        __syncthreads();
        if (dh == 0) w2q[b * U_ + n] = acc + part[tid];
    }
}

// ---------------- k_gemm_u: r1-flow GEMM + tanh + V-dot -> u_part ----------------
__global__ __launch_bounds__(512, 5)
void k_gemm_u(const float* __restrict__ value,
              const _Float16* __restrict__ W1T,  // [N=512][K=512] fp16
              const float* __restrict__ w2q,     // [32][512]
              const float* __restrict__ Vv,      // [512]
              float* __restrict__ u_part) {      // [2][65536]
    __shared__ __align__(16) _Float16 sA[64 * SAW];      //  5,120 B
    __shared__ __align__(16) _Float16 sB[256 * BK];      // 16,384 B (cell-swizzled)
    __shared__ float sRed[8][64];                        //  2,048 B

    const int tid  = threadIdx.x;
    const int wave = tid >> 6;
    const int lane = tid & 63;
    const int l15  = lane & 15;
    const int lg   = lane >> 4;          // 0..3
    const int bx   = blockIdx.x;
    // twin-swizzle: slices (bx, bx+8) share bx%8 -> same XCD, ~same time ->
    // the duplicated value read is XCD-L2/L3-served; HBM sees value once.
    const int sl   = (bx >> 3) & 1;
    const int rg   = ((bx >> 4) << 3) | (bx & 7);   // 0..1023
    const int m0   = rg * 64;
    const int b    = m0 >> 11;

    // B-DMA mapping (r7-validated, 0 conflicts): inst = wave*2+jj covers
    // n_local [inst*16, inst*16+16), full BK. Lane l fetches
    // W1T[n = sl*256 + inst*16 + (l&15)][k0 + (l>>4)*8 ..+8) -> LDS cell l.
    const int bnl  = l15;
    const int bhi8 = lg * 8;

    // A staging (r1-validated): thread t loads value[m0+(t>>3)][k0+(t&7)*4 ..+4)
    const int ar = tid >> 3;             // 0..63
    const int ac = (tid & 7) * 4;        // 0..28
    const float* aptr = value + (size_t)(m0 + ar) * D_ + ac;

    floatx4 acc[4][2];
    const floatx4 zero4 = {0.f, 0.f, 0.f, 0.f};
#pragma unroll
    for (int i = 0; i < 4; ++i)
#pragma unroll
        for (int j = 0; j < 2; ++j) acc[i][j] = zero4;

    for (int it = 0; it < 16; ++it) {
        const int k0 = it * BK;
        __syncthreads();   // protect LDS vs previous iter's frag reads
        {   // stage A (fp32 -> fp16)
            const floatx4 v4 = *(const floatx4*)(aptr + k0);
            half4_t h;
            h[0] = (_Float16)v4[0]; h[1] = (_Float16)v4[1];
            h[2] = (_Float16)v4[2]; h[3] = (_Float16)v4[3];
            *(half4_t*)(&sA[ar * SAW + ac]) = h;
        }
#pragma unroll
        for (int jj = 0; jj < 2; ++jj) {  // stage B (async direct-to-LDS)
            const int inst = wave * 2 + jj;
            const int n = sl * 256 + inst * 16 + bnl;
            gld_lds16(W1T + (size_t)n * D_ + k0 + bhi8, (void*)(&sB[inst * 512]));
        }
        __syncthreads();  // drains A stores + B DMA

        half8 af[4], bf[2];
#pragma unroll
        for (int mi = 0; mi < 4; ++mi)
            af[mi] = *(const half8*)(&sA[(mi * 16 + l15) * SAW + lg * 8]);
#pragma unroll
        for (int ni = 0; ni < 2; ++ni) {
            const int inst = wave * 2 + ni;
            bf[ni] = *(const half8*)(&sB[inst * 512 + (lg * 16 + l15) * 8]);
        }
#pragma unroll
        for (int ni = 0; ni < 2; ++ni)
#pragma unroll
            for (int mi = 0; mi < 4; ++mi)
                acc[mi][ni] = __builtin_amdgcn_mfma_f32_16x16x32_f16(
                    af[mi], bf[ni], acc[mi][ni], 0, 0, 0);
    }

    // epilogue: partial u over this wave's 32 cols
    float ps[4][4];
#pragma unroll
    for (int mi = 0; mi < 4; ++mi)
#pragma unroll
        for (int j = 0; j < 4; ++j) ps[mi][j] = 0.f;

#pragma unroll
    for (int ni = 0; ni < 2; ++ni) {
        const int n = sl * 256 + wave * 32 + ni * 16 + l15;   // C/D col = lane&15
        const float w2 = w2q[b * U_ + n];
        const float vv = Vv[n];
#pragma unroll
        for (int mi = 0; mi < 4; ++mi)
#pragma unroll
            for (int j = 0; j < 4; ++j)
                ps[mi][j] += vv * tanh_fast(acc[mi][ni][j] + w2);
    }
#pragma unroll
    for (int off = 1; off < 16; off <<= 1)
#pragma unroll
        for (int mi = 0; mi < 4; ++mi)
#pragma unroll
            for (int j = 0; j < 4; ++j)
                ps[mi][j] += __shfl_xor(ps[mi][j], off, 64);

    if (l15 == 0) {
#pragma unroll
        for (int mi = 0; mi < 4; ++mi)
#pragma unroll
            for (int j = 0; j < 4; ++j)
                sRed[wave][mi * 16 + lg * 4 + j] = ps[mi][j];  // row = lg*4 + j
    }
    __syncthreads();
    if (tid < 64) {
        float s = 0.f;
#pragma unroll
        for (int w = 0; w < 8; ++w) s += sRed[w][tid];
        u_part[(size_t)sl * M_ + m0 + tid] = s;
    }
}

// ---------------- k_post: softmax + top-4 + joint exact rescore + gather -------
__global__ __launch_bounds__(256)
void k_post(const float* __restrict__ u_part, const int* __restrict__ mask,
            const float* __restrict__ value, const float* __restrict__ W1,
            const float* __restrict__ w2q, const float* __restrict__ Vv,
            float* __restrict__ a_out, float* __restrict__ ctx_out) {
    __shared__ float sx[T_];
    __shared__ float rv[4];
    __shared__ int   ri[4];
    __shared__ float s_scalar;
    __shared__ int   s_cand[MAXC];
    __shared__ float s_score[MAXC];
    __shared__ __align__(16) float vrows[MAXC][D_];
    __shared__ int   s_t;

    const int b = blockIdx.x;
    const int tid = threadIdx.x;
    const int wave = tid >> 6, lane = tid & 63;

#pragma unroll
    for (int i = 0; i < 8; ++i) {
        const int t = tid * 8 + i;
        float x = u_part[b * T_ + t] + u_part[M_ + b * T_ + t];
        if (mask[b * T_ + t] == 0) x = -1e20f;
        sx[t] = x;
    }
    __syncthreads();

    for (int r = 0; r < MAXC; ++r) {
        float v = -INFINITY; int vi = 0;
#pragma unroll
        for (int i = 0; i < 8; ++i) {
            const int t = tid * 8 + i;
            const float x = sx[t];
            if (x > v) { v = x; vi = t; }
        }
        for (int off = 32; off > 0; off >>= 1) {
            const float ov = __shfl_down(v, off, 64);
            const int   oi = __shfl_down(vi, off, 64);
            if (ov > v || (ov == v && oi < vi)) { v = ov; vi = oi; }
        }
        if (lane == 0) { rv[wave] = v; ri[wave] = vi; }
        __syncthreads();
        if (tid == 0) {
            float bv = rv[0]; int bi = ri[0];
            for (int w = 1; w < 4; ++w)
                if (rv[w] > bv || (rv[w] == bv && ri[w] < bi)) { bv = rv[w]; bi = ri[w]; }
            s_cand[r] = bi;
            if (r == 0) s_scalar = bv;
            sx[bi] = -INFINITY;
        }
        __syncthreads();
    }
    const float mx = s_scalar;

    float zloc = 0.f;
    float evals[8];
#pragma unroll
    for (int i = 0; i < 8; ++i) {
        const int t = tid * 8 + i;
        float x = u_part[b * T_ + t] + u_part[M_ + b * T_ + t];
        if (mask[b * T_ + t] == 0) x = -1e20f;
        const float e = __expf(x - mx);
        evals[i] = e;
        zloc += e;
    }
    for (int off = 32; off > 0; off >>= 1) zloc += __shfl_down(zloc, off, 64);
    if (lane == 0) rv[wave] = zloc;
    __syncthreads();
    if (tid == 0) s_scalar = 1.0f / (rv[0] + rv[1] + rv[2] + rv[3]);
    __syncthreads();
    const float rz = s_scalar;
#pragma unroll
    for (int i = 0; i < 8; ++i) {
        const int t = tid * 8 + i;
        a_out[b * T_ + t] = evals[i] * rz;
    }

    // ---- joint exact fp32 rescore of the 4 candidates (one pass over W1) ----
#pragma unroll
    for (int ci = 0; ci < MAXC; ++ci) {
        const int t = s_cand[ci];
        vrows[ci][tid]       = value[((size_t)b * T_ + t) * D_ + tid];
        vrows[ci][tid + 256] = value[((size_t)b * T_ + t) * D_ + tid + 256];
    }
    __syncthreads();

    float dots[2][MAXC];
#pragma unroll
    for (int j = 0; j < 2; ++j)
#pragma unroll
        for (int ci = 0; ci < MAXC; ++ci) dots[j][ci] = 0.f;

    for (int d4 = 0; d4 < D_; d4 += 4) {
        floatx4 vr[MAXC];
#pragma unroll
        for (int ci = 0; ci < MAXC; ++ci)
            vr[ci] = *(const floatx4*)(&vrows[ci][d4]);
#pragma unroll
        for (int k = 0; k < 4; ++k) {
            const float w0 = W1[(size_t)(d4 + k) * U_ + tid];
            const float w1 = W1[(size_t)(d4 + k) * U_ + tid + 256];
#pragma unroll
            for (int ci = 0; ci < MAXC; ++ci) {
                dots[0][ci] = fmaf(vr[ci][k], w0, dots[0][ci]);
                dots[1][ci] = fmaf(vr[ci][k], w1, dots[1][ci]);
            }
        }
    }
    float sc[MAXC];
#pragma unroll
    for (int ci = 0; ci < MAXC; ++ci) {
        const float n0v = Vv[tid]       * tanhf(dots[0][ci] + w2q[b * U_ + tid]);
        const float n1v = Vv[tid + 256] * tanhf(dots[1][ci] + w2q[b * U_ + tid + 256]);
        sc[ci] = n0v + n1v;
    }
#pragma unroll
    for (int ci = 0; ci < MAXC; ++ci)
        for (int off = 32; off > 0; off >>= 1)
            sc[ci] += __shfl_down(sc[ci], off, 64);
    __syncthreads();
    if (lane == 0) {
#pragma unroll
        for (int ci = 0; ci < MAXC; ++ci)
            vrows[ci][wave] = sc[ci];
    }
    __syncthreads();
    if (tid == 0) {
#pragma unroll
        for (int ci = 0; ci < MAXC; ++ci) {
            const int t = s_cand[ci];
            float s = vrows[ci][0] + vrows[ci][1] + vrows[ci][2] + vrows[ci][3];
            if (mask[b * T_ + t] == 0) s = -1e20f;
            s_score[ci] = s;
        }
        float bv = s_score[0]; int bt = s_cand[0];
        for (int i = 1; i < MAXC; ++i) {
            if (s_score[i] > bv || (s_score[i] == bv && s_cand[i] < bt)) {
                bv = s_score[i]; bt = s_cand[i];
            }
        }
        s_t = bt;
    }
    __syncthreads();

    const int t = s_t;
    ctx_out[b * D_ + tid]       = value[((size_t)b * T_ + t) * D_ + tid];
    ctx_out[b * D_ + tid + 256] = value[((size_t)b * T_ + t) * D_ + tid + 256];
}

extern "C" void kernel_launch(void* const* d_in, const int* in_sizes, int n_in,
                              void* d_out, int out_size, void* d_ws, size_t ws_size,
                              hipStream_t stream) {
    const float* value = (const float*)d_in[0];   // [32,2048,512]
    const float* query = (const float*)d_in[1];   // [32,512]
    const int*   mask  = (const int*)d_in[2];     // [32,2048]
    const float* W1    = (const float*)d_in[3];   // [512,512]
    const float* W2    = (const float*)d_in[4];   // [512,512]
    const float* Vv    = (const float*)d_in[5];   // [512]

    char* ws = (char*)d_ws;
    _Float16* W1T    = (_Float16*)ws;                  // 524,288 B
    float*    w2q    = (float*)(ws + 524288);          //  65,536 B
    float*    u_part = (float*)(ws + 524288 + 65536);  // 524,288 B (2 x 65536 floats)

    float* ctx_out = (float*)d_out;              // [32,512]
    float* a_out   = (float*)d_out + B_ * D_;    // [32,2048]

    hipLaunchKernelGGL(k_prep,   dim3(192), dim3(256), 0, stream,
                       W1, query, W2, W1T, w2q);
    hipLaunchKernelGGL(k_gemm_u, dim3(2048), dim3(512), 0, stream,
                       value, W1T, w2q, Vv, u_part);
    hipLaunchKernelGGL(k_post,   dim3(32), dim3(256), 0, stream,
                       u_part, mask, value, W1, w2q, Vv, a_out, ctx_out);
}

// Round 9
// 270.027 us; speedup vs baseline: 1.2283x; 1.2283x over previous
//
#include <hip/hip_runtime.h>
#include <hip/hip_fp16.h>
#include <stdint.h>

// Problem constants
#define B_ 32
#define T_ 2048
#define D_ 512
#define U_ 512
#define M_ (B_ * T_)
#define MAXC 4
#define BK 32

typedef _Float16 half8   __attribute__((ext_vector_type(8)));
typedef float   floatx4  __attribute__((ext_vector_type(4)));

__device__ __forceinline__ float tanh_fast(float x) {
    float ax = fabsf(x);
    float e  = __expf(2.0f * ax);
    float t  = 1.0f - 2.0f / (e + 1.0f);
    return copysignf(t, x);
}

// async global->LDS, 16B/lane; dest = wave-uniform base + lane*16
__device__ __forceinline__ void gld_lds16(const void* gsrc, void* lds_dst) {
    typedef __attribute__((address_space(1))) const char gch;
    typedef __attribute__((address_space(3))) char lch;
    __builtin_amdgcn_global_load_lds((const gch*)(uintptr_t)gsrc,
                                     (lch*)(uint32_t)(uintptr_t)lds_dst,
                                     16, 0, 0);
}

// ---------------- k_prep: {W1 -> W1T fp16 transpose} + {w2q = query @ W2} ----
__global__ __launch_bounds__(256)
void k_prep(const float* __restrict__ W1, const float* __restrict__ query,
            const float* __restrict__ W2, _Float16* __restrict__ W1T,
            float* __restrict__ w2q) {
    const int bid = blockIdx.x;
    const int tid = threadIdx.x;
    if (bid < 64) {
        __shared__ float tile[64][65];
        const int bx = bid & 7, by = bid >> 3;
        const int k0 = bx * 64, n0 = by * 64;
        const int tx = tid & 63, ty = tid >> 6;
#pragma unroll
        for (int i = 0; i < 16; ++i) {
            int r = ty * 16 + i;
            tile[r][tx] = W1[(size_t)(k0 + r) * U_ + n0 + tx];
        }
        __syncthreads();
#pragma unroll
        for (int i = 0; i < 16; ++i) {
            int r = ty * 16 + i;
            W1T[(size_t)(n0 + r) * D_ + k0 + tx] = (_Float16)tile[tx][r];
        }
    } else {
        __shared__ float sq[D_];
        __shared__ float part[128];
        const int id = bid - 64;
        const int b  = id >> 2;
        const int nq = id & 3;
        sq[tid]       = query[b * D_ + tid];
        sq[tid + 256] = query[b * D_ + tid + 256];
        __syncthreads();
        const int n  = nq * 128 + (tid & 127);
        const int dh = tid >> 7;
        float acc = 0.f;
        const int d0 = dh * 256;
#pragma unroll 16
        for (int d = d0; d < d0 + 256; ++d)
            acc = fmaf(sq[d], W2[(size_t)d * U_ + n], acc);
        if (dh == 1) part[tid & 127] = acc;
        __syncthreads();
        if (dh == 0) w2q[b * U_ + n] = acc + part[tid];
    }
}

// ---------------- k_gemm_u: BM=128 x BN=512 x BK=32, all-DMA dbuf, 1 barrier/iter
// 1024 thr (16 waves). Wave (wv>>3) picks 64-row half, (wv&7) picks 64-col slab.
// LDS: sA fp32 [128][32] xor-swizzled units, sB fp16 [512][32] xor-swizzled.
__global__ __launch_bounds__(1024, 4)
void k_gemm_u(const float* __restrict__ value,
              const _Float16* __restrict__ W1T,  // [N=512][K=512] fp16
              const float* __restrict__ w2q,     // [32][512]
              const float* __restrict__ Vv,      // [512]
              float* __restrict__ u_out) {       // [65536]
    __shared__ __align__(16) float    sA[2][128 * 32];   // 2 x 16,384 B
    __shared__ __align__(16) _Float16 sB[2][512 * 32];   // 2 x 32,768 B
    __shared__ float sRed[16][64];                       // 4,096 B

    const int tid  = threadIdx.x;
    const int wv   = tid >> 6;           // 0..15
    const int l    = tid & 63;
    const int l15  = l & 15;
    const int lg   = l >> 4;             // 0..3
    const int m0   = blockIdx.x * 128;
    const int b    = m0 >> 11;
    const int wr   = (wv >> 3) * 64;     // wave row offset
    const int wc   = (wv & 7) * 64;      // wave col offset

    // A-DMA source: thread t -> row=t>>3, phys unit (l&7) holds logical unit (l&7)^(l>>3)
    const int a_row = tid >> 3;                      // 0..127
    const int a_lu  = (l & 7) ^ (l >> 3);            // logical 4-float unit
    const float* a_src = value + (size_t)(m0 + a_row) * D_ + a_lu * 4;
    // B-DMA source: inst j covers n=(wv*2+j)*16+(l>>2); phys unit (l&3) holds
    // logical 8-half unit (l&3)^((l>>3)&3)
    const int b_lu = (l & 3) ^ ((l >> 3) & 3);
    const int b_n0 = (l >> 2);

#define ISSUE(c, buf)                                                          \
    {                                                                          \
        gld_lds16(a_src + (c) * BK, (void*)(&sA[buf][wv * 256]));              \
        _Pragma("unroll")                                                      \
        for (int j = 0; j < 2; ++j) {                                          \
            const int inst = wv * 2 + j;                                       \
            const int n = inst * 16 + b_n0;                                    \
            gld_lds16(W1T + (size_t)n * D_ + (c) * BK + b_lu * 8,              \
                      (void*)(&sB[buf][inst * 512]));                          \
        }                                                                      \
    }

    ISSUE(0, 0);

    floatx4 acc[4][4];
    const floatx4 zero4 = {0.f, 0.f, 0.f, 0.f};
#pragma unroll
    for (int i = 0; i < 4; ++i)
#pragma unroll
        for (int j = 0; j < 4; ++j) acc[i][j] = zero4;

    __syncthreads();

    for (int c = 0; c < 16; ++c) {
        const int cur = c & 1;
        if (c < 15) ISSUE(c + 1, cur ^ 1);

        half8 af[4];
#pragma unroll
        for (int mi = 0; mi < 4; ++mi) {
            const int row = wr + mi * 16 + l15;
            const int r7  = l15 & 7;
            const int p0  = (lg * 2) ^ r7;
            const int p1  = (lg * 2 + 1) ^ r7;
            const floatx4 x0 = *(const floatx4*)(&sA[cur][row * 32 + p0 * 4]);
            const floatx4 x1 = *(const floatx4*)(&sA[cur][row * 32 + p1 * 4]);
            half8 h;
#pragma unroll
            for (int q = 0; q < 4; ++q) {
                h[q]     = (_Float16)x0[q];
                h[4 + q] = (_Float16)x1[q];
            }
            af[mi] = h;
        }
        half8 bf[4];
#pragma unroll
        for (int ni = 0; ni < 4; ++ni) {
            const int n = wc + ni * 16 + l15;
            const int p = lg ^ ((l15 >> 1) & 3);
            bf[ni] = *(const half8*)(&sB[cur][n * 32 + p * 8]);
        }
#pragma unroll
        for (int ni = 0; ni < 4; ++ni)
#pragma unroll
            for (int mi = 0; mi < 4; ++mi)
                acc[mi][ni] = __builtin_amdgcn_mfma_f32_16x16x32_f16(
                    af[mi], bf[ni], acc[mi][ni], 0, 0, 0);
        __syncthreads();   // DMA c+1 drained; buf cur free for c+2
    }
#undef ISSUE

    // epilogue: ps = vv*tanh(acc + w2), reduce over 16 col-lanes, then col-waves
    float ps[4][4];
#pragma unroll
    for (int mi = 0; mi < 4; ++mi)
#pragma unroll
        for (int j = 0; j < 4; ++j) ps[mi][j] = 0.f;
#pragma unroll
    for (int ni = 0; ni < 4; ++ni) {
        const int n = wc + ni * 16 + l15;    // C/D col = lane&15 (validated)
        const float w2 = w2q[b * U_ + n];
        const float vv = Vv[n];
#pragma unroll
        for (int mi = 0; mi < 4; ++mi)
#pragma unroll
            for (int j = 0; j < 4; ++j)
                ps[mi][j] += vv * tanh_fast(acc[mi][ni][j] + w2);
    }
#pragma unroll
    for (int off = 1; off < 16; off <<= 1)
#pragma unroll
        for (int mi = 0; mi < 4; ++mi)
#pragma unroll
            for (int j = 0; j < 4; ++j)
                ps[mi][j] += __shfl_xor(ps[mi][j], off, 64);

    if (l15 == 0) {
#pragma unroll
        for (int mi = 0; mi < 4; ++mi)
#pragma unroll
            for (int j = 0; j < 4; ++j)
                sRed[wv][mi * 16 + lg * 4 + j] = ps[mi][j];  // row=lg*4+j (validated)
    }
    __syncthreads();
    if (tid < 128) {
        const int half = tid >> 6, lr = tid & 63;
        float s = 0.f;
#pragma unroll
        for (int cw = 0; cw < 8; ++cw) s += sRed[half * 8 + cw][lr];
        u_out[m0 + tid] = s;
    }
}

// ---------------- k_post: top-4 select + softmax + zero cand_score ----------------
__global__ __launch_bounds__(256)
void k_post(const float* __restrict__ u, const int* __restrict__ mask,
            float* __restrict__ a_out, int* __restrict__ cand_t,
            float* __restrict__ cand_score) {
    __shared__ float sx[T_];
    __shared__ float rv[4];
    __shared__ int   ri[4];
    __shared__ float s_scalar;

    const int b = blockIdx.x;
    const int tid = threadIdx.x;
    const int wave = tid >> 6, lane = tid & 63;

    if (tid < MAXC) cand_score[b * MAXC + tid] = 0.f;

#pragma unroll
    for (int i = 0; i < 8; ++i) {
        const int t = tid * 8 + i;
        float x = u[b * T_ + t];
        if (mask[b * T_ + t] == 0) x = -1e20f;
        sx[t] = x;
    }
    __syncthreads();

    for (int r = 0; r < MAXC; ++r) {
        float v = -INFINITY; int vi = 0;
#pragma unroll
        for (int i = 0; i < 8; ++i) {
            const int t = tid * 8 + i;
            const float x = sx[t];
            if (x > v) { v = x; vi = t; }
        }
        for (int off = 32; off > 0; off >>= 1) {
            const float ov = __shfl_down(v, off, 64);
            const int   oi = __shfl_down(vi, off, 64);
            if (ov > v || (ov == v && oi < vi)) { v = ov; vi = oi; }
        }
        if (lane == 0) { rv[wave] = v; ri[wave] = vi; }
        __syncthreads();
        if (tid == 0) {
            float bv = rv[0]; int bi = ri[0];
            for (int w = 1; w < 4; ++w)
                if (rv[w] > bv || (rv[w] == bv && ri[w] < bi)) { bv = rv[w]; bi = ri[w]; }
            cand_t[b * MAXC + r] = bi;
            if (r == 0) s_scalar = bv;
            sx[bi] = -INFINITY;
        }
        __syncthreads();
    }
    const float mx = s_scalar;

    float zloc = 0.f;
    float evals[8];
#pragma unroll
    for (int i = 0; i < 8; ++i) {
        const int t = tid * 8 + i;
        float x = u[b * T_ + t];
        if (mask[b * T_ + t] == 0) x = -1e20f;
        const float e = __expf(x - mx);
        evals[i] = e;
        zloc += e;
    }
    for (int off = 32; off > 0; off >>= 1) zloc += __shfl_down(zloc, off, 64);
    if (lane == 0) rv[wave] = zloc;
    __syncthreads();
    if (tid == 0) s_scalar = 1.0f / (rv[0] + rv[1] + rv[2] + rv[3]);
    __syncthreads();
    const float rz = s_scalar;
#pragma unroll
    for (int i = 0; i < 8; ++i) {
        const int t = tid * 8 + i;
        a_out[b * T_ + t] = evals[i] * rz;
    }
}

// ---------------- k_resc: exact fp32 rescore, 256 blocks (32 b x 8 n-chunks) ----
__global__ __launch_bounds__(256)
void k_resc(const float* __restrict__ value, const float* __restrict__ W1,
            const float* __restrict__ w2q, const float* __restrict__ Vv,
            const int* __restrict__ cand_t, float* __restrict__ cand_score) {
    __shared__ __align__(16) float vrows[MAXC][D_];
    __shared__ float part[4][MAXC][64];
    const int b  = blockIdx.x >> 3;
    const int nc = blockIdx.x & 7;
    const int tid = threadIdx.x;

#pragma unroll
    for (int ci = 0; ci < MAXC; ++ci) {
        const int t = cand_t[b * MAXC + ci];
        vrows[ci][tid]       = value[((size_t)b * T_ + t) * D_ + tid];
        vrows[ci][tid + 256] = value[((size_t)b * T_ + t) * D_ + tid + 256];
    }
    __syncthreads();

    const int q  = tid >> 6;          // d-quarter (== wave)
    const int nl = tid & 63;
    const int n  = nc * 64 + nl;
    float dq[MAXC] = {0.f, 0.f, 0.f, 0.f};
    const int d0 = q * 128;
#pragma unroll 8
    for (int d = d0; d < d0 + 128; ++d) {
        const float w = W1[(size_t)d * U_ + n];
#pragma unroll
        for (int ci = 0; ci < MAXC; ++ci)
            dq[ci] = fmaf(vrows[ci][d], w, dq[ci]);
    }
#pragma unroll
    for (int ci = 0; ci < MAXC; ++ci) part[q][ci][nl] = dq[ci];
    __syncthreads();

    if (q == 0) {
        const float w2 = w2q[b * U_ + n];
        const float vv = Vv[n];
        float sc[MAXC];
#pragma unroll
        for (int ci = 0; ci < MAXC; ++ci) {
            const float dot = part[0][ci][nl] + part[1][ci][nl]
                            + part[2][ci][nl] + part[3][ci][nl];
            sc[ci] = vv * tanhf(dot + w2);
        }
#pragma unroll
        for (int off = 1; off < 64; off <<= 1)
#pragma unroll
            for (int ci = 0; ci < MAXC; ++ci)
                sc[ci] += __shfl_xor(sc[ci], off, 64);
        if (nl == 0) {
#pragma unroll
            for (int ci = 0; ci < MAXC; ++ci)
                atomicAdd(&cand_score[b * MAXC + ci], sc[ci]);
        }
    }
}

// ---------------- k_fin: exact argmax among candidates + context gather ----------
__global__ __launch_bounds__(256)
void k_fin(const float* __restrict__ value, const int* __restrict__ mask,
           const int* __restrict__ cand_t, const float* __restrict__ cand_score,
           float* __restrict__ ctx_out) {
    __shared__ int s_t;
    const int b = blockIdx.x;
    const int tid = threadIdx.x;
    if (tid == 0) {
        float bv = -INFINITY; int bt = cand_t[b * MAXC];
        for (int i = 0; i < MAXC; ++i) {
            const int   t = cand_t[b * MAXC + i];
            float s = cand_score[b * MAXC + i];
            if (mask[b * T_ + t] == 0) s = -1e20f;
            if (s > bv || (s == bv && t < bt)) { bv = s; bt = t; }
        }
        s_t = bt;
    }
    __syncthreads();
    const int t = s_t;
    ctx_out[b * D_ + tid]       = value[((size_t)b * T_ + t) * D_ + tid];
    ctx_out[b * D_ + tid + 256] = value[((size_t)b * T_ + t) * D_ + tid + 256];
}

extern "C" void kernel_launch(void* const* d_in, const int* in_sizes, int n_in,
                              void* d_out, int out_size, void* d_ws, size_t ws_size,
                              hipStream_t stream) {
    const float* value = (const float*)d_in[0];   // [32,2048,512]
    const float* query = (const float*)d_in[1];   // [32,512]
    const int*   mask  = (const int*)d_in[2];     // [32,2048]
    const float* W1    = (const float*)d_in[3];   // [512,512]
    const float* W2    = (const float*)d_in[4];   // [512,512]
    const float* Vv    = (const float*)d_in[5];   // [512]

    char* ws = (char*)d_ws;
    _Float16* W1T        = (_Float16*)ws;              // 524,288 B
    float*    w2q        = (float*)(ws + 524288);      //  65,536 B
    float*    u_ws       = (float*)(ws + 589824);      // 262,144 B
    int*      cand_t     = (int*)(ws + 851968);        //     512 B
    float*    cand_score = (float*)(ws + 852480);      //     512 B

    float* ctx_out = (float*)d_out;              // [32,512]
    float* a_out   = (float*)d_out + B_ * D_;    // [32,2048]

    hipLaunchKernelGGL(k_prep,   dim3(192), dim3(256), 0, stream,
                       W1, query, W2, W1T, w2q);
    hipLaunchKernelGGL(k_gemm_u, dim3(M_ / 128), dim3(1024), 0, stream,
                       value, W1T, w2q, Vv, u_ws);
    hipLaunchKernelGGL(k_post,   dim3(32), dim3(256), 0, stream,
                       u_ws, mask, a_out, cand_t, cand_score);
    hipLaunchKernelGGL(k_resc,   dim3(256), dim3(256), 0, stream,
                       value, W1, w2q, Vv, cand_t, cand_score);
    hipLaunchKernelGGL(k_fin,    dim3(32), dim3(256), 0, stream,
                       value, mask, cand_t, cand_score, ctx_out);
}